// Round 9
// baseline (8903.811 us; speedup 1.0000x reference)
//
#include <hip/hip_runtime.h>
#include <cstdint>

#define NB 16      // clouds
#define NP 4096    // points per cloud
#define MC 1024    // FPS centers per cloud
#define KNN 64     // neighbors
#define CIN 64     // input feature dim
#define HID 64
#define OUTD 128

typedef __attribute__((ext_vector_type(8))) short bf16x8;
typedef __attribute__((ext_vector_type(4))) float f32x4;
typedef unsigned long long ull;
typedef unsigned short ushort_t;

#define F32_INF __int_as_float(0x7f800000)
#define SCOPE_AGENT __HIP_MEMORY_SCOPE_AGENT

// Bit-exact (vs numpy f32) squared distance: no FMA contraction, numpy sum order.
__device__ __forceinline__ float dist2e(float ax, float ay, float az,
                                        float bx, float by, float bz) {
  float dx = __fsub_rn(ax, bx);
  float dy = __fsub_rn(ay, by);
  float dz = __fsub_rn(az, bz);
  return __fadd_rn(__fadd_rn(__fmul_rn(dx, dx), __fmul_rn(dy, dy)), __fmul_rn(dz, dz));
}

// f32 -> bf16 with round-to-nearest-even.
__device__ __forceinline__ ushort_t f2bf(float f) {
  unsigned u = __float_as_uint(f);
  unsigned r = (u + 0x7FFFu + ((u >> 16) & 1u)) >> 16;
  return (ushort_t)r;
}

// ---- DPP helpers: 64-bit key max-reduce on the VALU pipe ----
template <int CTRL>
__device__ __forceinline__ ull kshift(ull k) {
  int lo = (int)(unsigned)(k & 0xffffffffULL);
  int hi = (int)(unsigned)(k >> 32);
  lo = __builtin_amdgcn_update_dpp(lo, lo, CTRL, 0xf, 0xf, false);
  hi = __builtin_amdgcn_update_dpp(hi, hi, CTRL, 0xf, 0xf, false);
  return ((ull)(unsigned)hi << 32) | (ull)(unsigned)lo;
}
template <int CTRL>
__device__ __forceinline__ ull kred(ull k) {
  ull o = kshift<CTRL>(k);
  return (o > k) ? o : k;
}

// ---------- Prep helper: W -> MFMA B-fragment layout, agent-atomic stores ----------
__device__ __forceinline__ void wfrag_atomic(const float* __restrict__ W,
                                             ushort_t* __restrict__ out,
                                             int e, int KS, int K, int N) {
  int ln = e & 63, t2 = e >> 6;
  int ks = t2 % KS, nt = t2 / KS;
  int n = nt * 16 + (ln & 15);
  int kb = ks * 32 + ((ln >> 4) & 3) * 8;
  ull lo = 0, hi = 0;
#pragma unroll
  for (int j = 0; j < 4; ++j) {
    int k = kb + j;
    float v = (k < K) ? W[(size_t)k * N + n] : 0.f;
    lo |= (ull)f2bf(v) << (16 * j);
  }
#pragma unroll
  for (int j = 4; j < 8; ++j) {
    int k = kb + j;
    float v = (k < K) ? W[(size_t)k * N + n] : 0.f;
    hi |= (ull)f2bf(v) << (16 * (j - 4));
  }
  ull* q = (ull*)(out + (size_t)e * 8);
  __hip_atomic_store(q + 0, lo, __ATOMIC_RELAXED, SCOPE_AGENT);
  __hip_atomic_store(q + 1, hi, __ATOMIC_RELAXED, SCOPE_AGENT);
}

// =================== ONE fused kernel: 16 producer + 512 consumer blocks ===================
// Producer (blk<16): r3-proven FPS core + progressive ctr publish (agent atomics,
//   chunk of 32 rows, flag = rows drained; barrier between issue and flag guarantees
//   vmcnt retirement). LDS: px/py/pz SoA 48K + whist 4K + kbuf.
// Consumer (blk>=16): prep slice (atomic stores) -> release prep_cnt -> acquire-wait all
//   prep -> 8 units/wave: acquire-poll progress[b] (s_sleep backoff; NOT the r4 LDS
//   spin-storm — sleeping waves don't issue), tau-neigh (r8) -> register jg -> MFMA mlp
//   (r8). Per-wave 9216B LDS region: ld/li/nsel overlay hbuf (sequential within wave).
// Residency (no deadlock): LDS max 53312 -> 3 blk/CU -> 768 >= 528; VGPR capped by
//   __launch_bounds__(256,3) <= 170. All blocks resident at t=0.
#define SMEM_BYTES 53312
#define HSTRIDE 72   // bf16/row: 144 B, 16B-aligned, 2-way-conflict-free b128

__global__ __launch_bounds__(256, 3) void fused_kernel(
    const float* __restrict__ point, const float* __restrict__ xyz,
    const float* __restrict__ W1, const float* __restrict__ W2, const float* __restrict__ W3,
    const float* __restrict__ b1, const float* __restrict__ b2, const float* __restrict__ b3,
    unsigned* __restrict__ flags,    // progress[b] = flags[b*32]; prep_cnt = flags[512]
    float* __restrict__ ctr,
    ushort_t* __restrict__ xyzbf, ushort_t* __restrict__ w1f,
    ushort_t* __restrict__ w2f, ushort_t* __restrict__ w3f,
    float* __restrict__ out, float* __restrict__ cent_out, float* __restrict__ batch_out) {
  __shared__ __align__(16) char smem[SMEM_BYTES];
  const int blk = blockIdx.x, t = threadIdx.x;
  const int lane = t & 63, wv = t >> 6;
  unsigned* ctru = (unsigned*)ctr;

  if (blk < NB) {
    // ================= PRODUCER: FPS for cloud b =================
    float* px = (float*)smem;                 // 16384 B
    float* py = (float*)(smem + 16384);
    float* pz = (float*)(smem + 32768);
    int* whist = (int*)(smem + 49152);        // 4096 B
    ull (*kbuf)[4] = (ull (*)[4])(smem + 53248);
    const int b = blk;
    const float* p = point + (size_t)b * NP * 3;
    for (int i = t; i < NP; i += 256) {
      px[i] = p[3*i]; py[i] = p[3*i+1]; pz[i] = p[3*i+2];
    }
    if (t == 0) whist[0] = 0;     // sample 0 is index 0
    __syncthreads();
    float qx[16], qy[16], qz[16], d[16];
#pragma unroll
    for (int r = 0; r < 16; ++r) {
      int i = t * 16 + r;
      qx[r] = px[i]; qy[r] = py[i]; qz[r] = pz[i];
      d[r] = F32_INF;             // min(inf, d0) == d0 exactly
    }
    int w = 0;
    const size_t cb = (size_t)b * MC * 3;
    for (int it = 1; it < MC; ++it) {
      float wx = px[w], wy = py[w], wz = pz[w];
      float bd = -1.0f; int br = 0;
#pragma unroll
      for (int r = 0; r < 16; ++r) {   // fused min-update + first-max argmax
        float nd = dist2e(qx[r], qy[r], qz[r], wx, wy, wz);
        float dv = fminf(d[r], nd);
        d[r] = dv;
        if (dv > bd) { bd = dv; br = r; }
      }
      unsigned gi = (unsigned)(t * 16 + br);
      ull key = ((ull)__float_as_uint(bd) << 32) | (ull)(unsigned)~gi;
      key = kred<0x111>(key);  // row_shr:1
      key = kred<0x112>(key);  // row_shr:2
      key = kred<0x114>(key);  // row_shr:4
      key = kred<0x118>(key);  // row_shr:8
      key = kred<0x142>(key);  // row_bcast:15
      key = kred<0x143>(key);  // row_bcast:31 -> lane 63 = wave max
      const int par = it & 1;
      if (lane == 63) kbuf[par][wv] = key;
      __syncthreads();
      ull k0 = kbuf[par][0], k1 = kbuf[par][1], k2 = kbuf[par][2], k3 = kbuf[par][3];
      ull ka = (k0 > k1) ? k0 : k1;
      ull kb2 = (k2 > k3) ? k2 : k3;
      ull km = (ka > kb2) ? ka : kb2;
      w = (int)~(unsigned)(km & 0xffffffffULL);
      if (t == 0) whist[it] = w;
      if ((it & 31) == 0) {            // progressive publish, every 32 iters
        if (t < 96) {                  // rows [it-32, it): whist entries all visible
          int rq = t / 3, comp = t - rq * 3;
          int row = (it - 32) + rq;
          int wi = whist[row];
          float val = (comp == 0) ? px[wi] : ((comp == 1) ? py[wi] : pz[wi]);
          __hip_atomic_store(ctru + cb + (size_t)row * 3 + comp,
                             __float_as_uint(val), __ATOMIC_RELAXED, SCOPE_AGENT);
        }
        // chunk issued at it-32 has passed >=1 barrier (vmcnt drained) -> announce
        if (t == 0)
          __hip_atomic_store(flags + b * 32, (unsigned)(it - 32),
                             __ATOMIC_RELEASE, SCOPE_AGENT);
      }
    }
    __syncthreads();
    if (t < 96) {                      // final rows [992, 1024)
      int rq = t / 3, comp = t - rq * 3;
      int row = 992 + rq;
      int wi = whist[row];
      float val = (comp == 0) ? px[wi] : ((comp == 1) ? py[wi] : pz[wi]);
      __hip_atomic_store(ctru + cb + (size_t)row * 3 + comp,
                         __float_as_uint(val), __ATOMIC_RELAXED, SCOPE_AGENT);
    }
    for (int s = t; s < MC; s += 256) {   // outputs 1 & 2 (normal stores, kernel-end flush)
      int wi = whist[s];
      size_t o = (size_t)b * MC + s;
      cent_out[3*o] = px[wi]; cent_out[3*o+1] = py[wi]; cent_out[3*o+2] = pz[wi];
      batch_out[o] = (float)b;           // batch = arange // NP == cloud index
    }
    __syncthreads();                     // drains all waves' atomic stores
    if (t == 0)
      __hip_atomic_store(flags + b * 32, 1024u, __ATOMIC_RELEASE, SCOPE_AGENT);
    return;
  }

  // ================= CONSUMER =================
  const int ck = blk - NB;               // 0..511
  {  // ---- prep slice: xyz -> bf16 (8192 floats/block), agent-atomic u64 stores ----
    const float* src = xyz + (size_t)ck * 8192;
    ull* dst = (ull*)(xyzbf + (size_t)ck * 8192);
    for (int e = t; e < 2048; e += 256) {
      float4 v = *(const float4*)(src + (size_t)e * 4);
      ull u = (ull)f2bf(v.x) | ((ull)f2bf(v.y) << 16) |
              ((ull)f2bf(v.z) << 32) | ((ull)f2bf(v.w) << 48);
      __hip_atomic_store(dst + e, u, __ATOMIC_RELAXED, SCOPE_AGENT);
    }
    if (ck < 18 && t < 128) {            // 2304 weight-frag entries, 128/block
      int e = ck * 128 + t;
      if (e < 768)       wfrag_atomic(W1, w1f, e, 3, CIN + 3, HID);
      else if (e < 1280) wfrag_atomic(W2, w2f, e - 768, 2, HID, HID);
      else               wfrag_atomic(W3, w3f, e - 1280, 2, HID, OUTD);
    }
  }
  __syncthreads();                       // all block stores vmcnt-drained
  __threadfence();
  if (t == 0)
    __hip_atomic_fetch_add(flags + 512, 1u, __ATOMIC_ACQ_REL, SCOPE_AGENT);
  while (__hip_atomic_load(flags + 512, __ATOMIC_ACQUIRE, SCOPE_AGENT) < 512u)
    __builtin_amdgcn_s_sleep(8);

  const int b = ck >> 5;                 // cloud
  const int jb = ck & 31;                // within-cloud block
  char* wreg = smem + wv * 9216;         // per-wave region
  float* ld = (float*)wreg;              // scan scratch (dead before hbuf use)
  int*   li = (int*)(wreg + 2048);
  int*   nsel = (int*)(wreg + 4096);
  ushort_t* hb = (ushort_t*)wreg;        // 64 x HSTRIDE hbuf overlays scratch
  const int quad = lane >> 4, col16 = lane & 15;
  const size_t bbase = (size_t)b * NP;
  const float* p = point + bbase * 3;
  const float R2 = (float)(0.2 * 0.2);

  for (int u = 0; u < 8; ++u) {
    const int lc = jb * 32 + u * 4 + wv;
    const int c = b * MC + lc;
    while (__hip_atomic_load(flags + b * 32, __ATOMIC_ACQUIRE, SCOPE_AGENT)
           < (unsigned)(lc + 1))
      __builtin_amdgcn_s_sleep(8);
    const float cx = __uint_as_float(
        __hip_atomic_load(ctru + (size_t)c * 3 + 0, __ATOMIC_RELAXED, SCOPE_AGENT));
    const float cy = __uint_as_float(
        __hip_atomic_load(ctru + (size_t)c * 3 + 1, __ATOMIC_RELAXED, SCOPE_AGENT));
    const float cz = __uint_as_float(
        __hip_atomic_load(ctru + (size_t)c * 3 + 2, __ATOMIC_RELAXED, SCOPE_AGENT));

    // ---- neigh: compact in-ball candidates, tau set-selection (r8 proven) ----
    int cnt = 0;
    for (int s = 0; s < NP / 64; ++s) {
      int jj = s * 64 + lane;
      float d2 = dist2e(cx, cy, cz, p[3*jj], p[3*jj+1], p[3*jj+2]);
      bool v = d2 < R2;
      ull m = __ballot(v);
      if (v) {
        int pos = cnt + __popcll(m & ((1ull << lane) - 1ull));
        if (pos < 512) { ld[pos] = d2; li[pos] = jj; }
      }
      cnt += __popcll(m);
    }
    if (cnt > 512) cnt = 512;
    const int nv = (cnt < KNN) ? cnt : KNN;
    int jg;
    if (cnt <= KNN) {
      jg = (lane < cnt) ? li[lane] : 0;  // set-equivalent under masked max-agg
    } else {
      unsigned ob[8]; int oi[8];
#pragma unroll
      for (int r = 0; r < 8; ++r) {
        int s2 = lane + r * 64;
        if (s2 < cnt) { ob[r] = __float_as_uint(ld[s2]); oi[r] = li[s2]; }
        else { ob[r] = 0xFFFFFFFFu; oi[r] = 0; }
      }
      unsigned L = 0u, H = 0x3D23D70Au;  // all candidate bits < bits(0.04f)
      while (L < H) {                    // tau = KNN-th smallest d2 bit pattern
        unsigned mid = (L + H) >> 1;
        int cle = 0;
#pragma unroll
        for (int r = 0; r < 8; ++r) cle += (int)__popcll(__ballot(ob[r] <= mid));
        if (cle >= KNN) H = mid; else L = mid + 1;
      }
      const unsigned tau = H;
      int c_lt = 0;
#pragma unroll
      for (int r = 0; r < 8; ++r) c_lt += (int)__popcll(__ballot(ob[r] < tau));
      const int need = KNN - c_lt;
      const ull below = (1ull << lane) - 1ull;
      int outpos = 0, eqc = 0;
#pragma unroll
      for (int r = 0; r < 8; ++r) {      // slot order == index order (stable ties)
        ull meq = __ballot(ob[r] == tau);
        int eqrank = eqc + (int)__popcll(meq & below);
        bool sel = (ob[r] < tau) || ((ob[r] == tau) && (eqrank < need));
        ull msel = __ballot(sel);
        if (sel) nsel[outpos + (int)__popcll(msel & below)] = oi[r];
        outpos += (int)__popcll(msel);
        eqc += (int)__popcll(meq);
      }
      jg = nsel[lane];
    }

    // ---- MFMA bf16 MLP for center c (r8 body; jg/nv/cx.. in registers) ----
    const float* pp = point + (bbase + jg) * 3;
    const float dx = pp[0] - cx, dy = pp[1] - cy, dz = pp[2] - cz;
    bf16x8 a1[4][2];
    bf16x8 a2[4];
#pragma unroll
    for (int mt = 0; mt < 4; ++mt) {
      int srcl = mt * 16 + col16;
      int jmt = __shfl(jg, srcl);
      const ushort_t* rp = xyzbf + (bbase + (size_t)jmt) * CIN + quad * 8;
      a1[mt][0] = *(const bf16x8*)(rp);
      a1[mt][1] = *(const bf16x8*)(rp + 32);
      float ddx = __shfl(dx, srcl), ddy = __shfl(dy, srcl), ddz = __shfl(dz, srcl);
      bf16x8 t2 = {0, 0, 0, 0, 0, 0, 0, 0};
      if (quad == 0) {
        t2[0] = (short)f2bf(ddx); t2[1] = (short)f2bf(ddy); t2[2] = (short)f2bf(ddz);
      }
      a2[mt] = t2;
    }
    bf16x8 bw1[4][3];
#pragma unroll
    for (int nt = 0; nt < 4; ++nt)
#pragma unroll
      for (int ks = 0; ks < 3; ++ks)
        bw1[nt][ks] = *(const bf16x8*)(w1f + ((size_t)(nt * 3 + ks) * 64 + lane) * 8);
    f32x4 acc1[4][4];
#pragma unroll
    for (int nt = 0; nt < 4; ++nt) {
      float bv = b1[nt * 16 + col16];
#pragma unroll
      for (int mt = 0; mt < 4; ++mt) { f32x4 v = {bv, bv, bv, bv}; acc1[mt][nt] = v; }
    }
#pragma unroll
    for (int mt = 0; mt < 4; ++mt)
#pragma unroll
      for (int nt = 0; nt < 4; ++nt) {
        acc1[mt][nt] = __builtin_amdgcn_mfma_f32_16x16x32_bf16(a1[mt][0], bw1[nt][0], acc1[mt][nt], 0, 0, 0);
        acc1[mt][nt] = __builtin_amdgcn_mfma_f32_16x16x32_bf16(a1[mt][1], bw1[nt][1], acc1[mt][nt], 0, 0, 0);
        acc1[mt][nt] = __builtin_amdgcn_mfma_f32_16x16x32_bf16(a2[mt],    bw1[nt][2], acc1[mt][nt], 0, 0, 0);
      }
#pragma unroll
    for (int mt = 0; mt < 4; ++mt)
#pragma unroll
      for (int nt = 0; nt < 4; ++nt)
#pragma unroll
        for (int reg = 0; reg < 4; ++reg) {
          int row = quad * 4 + reg + mt * 16;
          hb[row * HSTRIDE + col16 + nt * 16] = f2bf(fmaxf(acc1[mt][nt][reg], 0.f));
        }
    bf16x8 a21[4][2];
#pragma unroll
    for (int mt = 0; mt < 4; ++mt)
#pragma unroll
      for (int ks = 0; ks < 2; ++ks)
        a21[mt][ks] = *(const bf16x8*)(hb + (col16 + mt * 16) * HSTRIDE + ks * 32 + quad * 8);
    bf16x8 bw2[4][2];
#pragma unroll
    for (int nt = 0; nt < 4; ++nt)
#pragma unroll
      for (int ks = 0; ks < 2; ++ks)
        bw2[nt][ks] = *(const bf16x8*)(w2f + ((size_t)(nt * 2 + ks) * 64 + lane) * 8);
    f32x4 acc2[4][4];
#pragma unroll
    for (int nt = 0; nt < 4; ++nt) {
      float bv = b2[nt * 16 + col16];
#pragma unroll
      for (int mt = 0; mt < 4; ++mt) { f32x4 v = {bv, bv, bv, bv}; acc2[mt][nt] = v; }
    }
#pragma unroll
    for (int mt = 0; mt < 4; ++mt)
#pragma unroll
      for (int nt = 0; nt < 4; ++nt) {
        acc2[mt][nt] = __builtin_amdgcn_mfma_f32_16x16x32_bf16(a21[mt][0], bw2[nt][0], acc2[mt][nt], 0, 0, 0);
        acc2[mt][nt] = __builtin_amdgcn_mfma_f32_16x16x32_bf16(a21[mt][1], bw2[nt][1], acc2[mt][nt], 0, 0, 0);
      }
#pragma unroll
    for (int mt = 0; mt < 4; ++mt)
#pragma unroll
      for (int nt = 0; nt < 4; ++nt)
#pragma unroll
        for (int reg = 0; reg < 4; ++reg) {
          int row = quad * 4 + reg + mt * 16;
          hb[row * HSTRIDE + col16 + nt * 16] = f2bf(fmaxf(acc2[mt][nt][reg], 0.f));
        }
    bf16x8 a3[4][2];
#pragma unroll
    for (int mt = 0; mt < 4; ++mt)
#pragma unroll
      for (int ks = 0; ks < 2; ++ks)
        a3[mt][ks] = *(const bf16x8*)(hb + (col16 + mt * 16) * HSTRIDE + ks * 32 + quad * 8);
#pragma unroll
    for (int pass = 0; pass < 2; ++pass) {
      bf16x8 bw3[4][2];
#pragma unroll
      for (int nt = 0; nt < 4; ++nt)
#pragma unroll
        for (int ks = 0; ks < 2; ++ks)
          bw3[nt][ks] = *(const bf16x8*)(w3f + ((size_t)((pass * 4 + nt) * 2 + ks) * 64 + lane) * 8);
      f32x4 acc3[4][4];
#pragma unroll
      for (int nt = 0; nt < 4; ++nt) {
        float bv = b3[pass * 64 + nt * 16 + col16];
#pragma unroll
        for (int mt = 0; mt < 4; ++mt) { f32x4 v = {bv, bv, bv, bv}; acc3[mt][nt] = v; }
      }
#pragma unroll
      for (int mt = 0; mt < 4; ++mt)
#pragma unroll
        for (int nt = 0; nt < 4; ++nt) {
          acc3[mt][nt] = __builtin_amdgcn_mfma_f32_16x16x32_bf16(a3[mt][0], bw3[nt][0], acc3[mt][nt], 0, 0, 0);
          acc3[mt][nt] = __builtin_amdgcn_mfma_f32_16x16x32_bf16(a3[mt][1], bw3[nt][1], acc3[mt][nt], 0, 0, 0);
        }
#pragma unroll
      for (int nt = 0; nt < 4; ++nt) {
        float m = -1.0e30f;
#pragma unroll
        for (int mt = 0; mt < 4; ++mt)
#pragma unroll
          for (int reg = 0; reg < 4; ++reg) {
            int row = quad * 4 + reg + mt * 16;
            float v = fmaxf(acc3[mt][nt][reg], 0.f);
            m = fmaxf(m, (row < nv) ? v : -1.0e30f);
          }
        m = fmaxf(m, __shfl_xor(m, 16));
        m = fmaxf(m, __shfl_xor(m, 32));
        if (quad == 0)
          out[(size_t)c * OUTD + pass * 64 + nt * 16 + col16] = m;
      }
    }
  }
}

extern "C" void kernel_launch(void* const* d_in, const int* in_sizes, int n_in,
                              void* d_out, int out_size, void* d_ws, size_t ws_size,
                              hipStream_t stream) {
  const float* xyz   = (const float*)d_in[0];
  const float* point = (const float*)d_in[1];
  // d_in[2] = batch (values == cloud index by construction), d_in[3] = num_samples (64)
  const float* W1 = (const float*)d_in[4];
  const float* b1 = (const float*)d_in[5];
  const float* W2 = (const float*)d_in[6];
  const float* b2 = (const float*)d_in[7];
  const float* W3 = (const float*)d_in[8];
  const float* b3 = (const float*)d_in[9];

  float* out       = (float*)d_out;                     // [16384,128]
  float* cent_out  = out + (size_t)NB * MC * OUTD;      // [16384,3]
  float* batch_out = cent_out + (size_t)NB * MC * 3;    // [16384] (f32 values)

  char* ws = (char*)d_ws;
  unsigned* flags  = (unsigned*)ws;                         // 4096 B (progress+prep_cnt)
  float* ctr       = (float*)(ws + 4096);                   // 196608 B
  ushort_t* xyzbf  = (ushort_t*)(ws + 4456448);             // 8 MB
  ushort_t* w1f    = (ushort_t*)(ws + 4456448 + 8388608);   // 12288 B
  ushort_t* w2f    = (ushort_t*)(ws + 12845056 + 12288);    // 8192 B
  ushort_t* w3f    = (ushort_t*)(ws + 12857344 + 8192);     // 16384 B

  // Flags MUST be zeroed (harness poisons ws with 0xAA, which would read as "ready").
  hipMemsetAsync(ws, 0, 4096, stream);
  fused_kernel<<<NB + 512, 256, 0, stream>>>(
      point, xyz, W1, W2, W3, b1, b2, b3,
      flags, ctr, xyzbf, w1f, w2f, w3f, out, cent_out, batch_out);
}

// Round 10
// 1027.682 us; speedup vs baseline: 8.6640x; 8.6640x over previous
//
#include <hip/hip_runtime.h>
#include <cstdint>

#define NB 16      // clouds
#define NP 4096    // points per cloud
#define MC 1024    // FPS centers per cloud
#define KNN 64     // neighbors
#define CIN 64     // input feature dim
#define HID 64
#define OUTD 128

typedef __attribute__((ext_vector_type(8))) short bf16x8;
typedef __attribute__((ext_vector_type(4))) float f32x4;
typedef unsigned long long ull;
typedef unsigned short ushort_t;

#define F32_INF __int_as_float(0x7f800000)
#define SCOPE_AGENT __HIP_MEMORY_SCOPE_AGENT

// Bit-exact (vs numpy f32) squared distance: no FMA contraction, numpy sum order.
__device__ __forceinline__ float dist2e(float ax, float ay, float az,
                                        float bx, float by, float bz) {
  float dx = __fsub_rn(ax, bx);
  float dy = __fsub_rn(ay, by);
  float dz = __fsub_rn(az, bz);
  return __fadd_rn(__fadd_rn(__fmul_rn(dx, dx), __fmul_rn(dy, dy)), __fmul_rn(dz, dz));
}

// f32 -> bf16 with round-to-nearest-even.
__device__ __forceinline__ ushort_t f2bf(float f) {
  unsigned u = __float_as_uint(f);
  unsigned r = (u + 0x7FFFu + ((u >> 16) & 1u)) >> 16;
  return (ushort_t)r;
}

// ---- DPP helpers: 64-bit key max-reduce on the VALU pipe ----
template <int CTRL>
__device__ __forceinline__ ull kshift(ull k) {
  int lo = (int)(unsigned)(k & 0xffffffffULL);
  int hi = (int)(unsigned)(k >> 32);
  lo = __builtin_amdgcn_update_dpp(lo, lo, CTRL, 0xf, 0xf, false);
  hi = __builtin_amdgcn_update_dpp(hi, hi, CTRL, 0xf, 0xf, false);
  return ((ull)(unsigned)hi << 32) | (ull)(unsigned)lo;
}
template <int CTRL>
__device__ __forceinline__ ull kred(ull k) {
  ull o = kshift<CTRL>(k);
  return (o > k) ? o : k;
}

// ---------- Kernel 1: prep (normal stores; kernel-boundary release publishes) ----------
__device__ __forceinline__ void wfrag_entry(const float* __restrict__ W,
                                            ushort_t* __restrict__ out,
                                            int e, int KS, int K, int N) {
  int ln = e & 63, t2 = e >> 6;
  int ks = t2 % KS, nt = t2 / KS;
  int n = nt * 16 + (ln & 15);
  int kb = ks * 32 + ((ln >> 4) & 3) * 8;
#pragma unroll
  for (int j = 0; j < 8; ++j) {
    int k = kb + j;
    float v = (k < K) ? W[(size_t)k * N + n] : 0.f;
    out[(size_t)e * 8 + j] = f2bf(v);
  }
}

__global__ __launch_bounds__(256) void prep_kernel(
    const float* __restrict__ xyz,
    const float* __restrict__ W1, const float* __restrict__ W2, const float* __restrict__ W3,
    ushort_t* __restrict__ xyzbf, ushort_t* __restrict__ w1f,
    ushort_t* __restrict__ w2f, ushort_t* __restrict__ w3f) {
  const int blk = blockIdx.x, t = threadIdx.x;
  if (blk < 4096) {
    size_t i = ((size_t)blk * 256 + t) * 4;
    float4 v = *(const float4*)(xyz + i);
    unsigned lo = (unsigned)f2bf(v.x) | ((unsigned)f2bf(v.y) << 16);
    unsigned hi = (unsigned)f2bf(v.z) | ((unsigned)f2bf(v.w) << 16);
    uint2 o; o.x = lo; o.y = hi;
    *(uint2*)(xyzbf + i) = o;
  } else {
    for (int e = t; e < 4 * 3 * 64; e += 256) wfrag_entry(W1, w1f, e, 3, CIN + 3, HID);
    for (int e = t; e < 4 * 2 * 64; e += 256) wfrag_entry(W2, w2f, e, 2, HID, HID);
    for (int e = t; e < 8 * 2 * 64; e += 256) wfrag_entry(W3, w3f, e, 2, HID, OUTD);
  }
}

// ========== Kernel 2: 16 FPS producer blocks + 512 neigh+mlp consumer blocks ==========
// Producer: r3-proven FPS core at s_setprio(3) + progressive ctr publish (relaxed agent
//   atomic stores; flag released only for rows drained by a prior barrier's vmcnt(0)).
// Consumer: poll progress with RELAXED agent loads + s_sleep — NEVER acquire: on gfx950
//   an agent-acquire load emits buffer_inv sc0 sc1, invalidating L1+L2 every poll
//   (r9's 98->188MB FETCH storm). Relaxed sc1 loads read the L3 coherence point with no
//   invalidation. ctr read the same way; correctness: producer drains ctr stores before
//   the release flag; consumer issues ctr loads only after observing the flag.
// No prep barrier, no consumer->producer waits => producers (blocks 0..15, scheduled
//   first) never block on consumers: deadlock-free regardless of residency.
#define SMEM_BYTES 53312
#define HSTRIDE 72   // bf16/row: 144 B, 16B-aligned, 2-way-conflict-free b128

__global__ __launch_bounds__(256, 3) void fps_cons_kernel(
    const float* __restrict__ point,
    const float* __restrict__ b1, const float* __restrict__ b2, const float* __restrict__ b3,
    unsigned* __restrict__ flags,    // progress[b] = flags[b*32] (one cache line per cloud)
    float* __restrict__ ctr,
    const ushort_t* __restrict__ xyzbf, const ushort_t* __restrict__ w1f,
    const ushort_t* __restrict__ w2f, const ushort_t* __restrict__ w3f,
    float* __restrict__ out, float* __restrict__ cent_out, float* __restrict__ batch_out) {
  __shared__ __align__(16) char smem[SMEM_BYTES];
  const int blk = blockIdx.x, t = threadIdx.x;
  const int lane = t & 63, wv = t >> 6;
  unsigned* ctru = (unsigned*)ctr;

  if (blk < NB) {
    // ================= PRODUCER: FPS for cloud b =================
    __builtin_amdgcn_s_setprio(3);            // protect the serial critical path
    float* px = (float*)smem;                 // 16384 B
    float* py = (float*)(smem + 16384);
    float* pz = (float*)(smem + 32768);
    int* whist = (int*)(smem + 49152);        // 4096 B
    ull (*kbuf)[4] = (ull (*)[4])(smem + 53248);
    const int b = blk;
    const float* p = point + (size_t)b * NP * 3;
    for (int i = t; i < NP; i += 256) {
      px[i] = p[3*i]; py[i] = p[3*i+1]; pz[i] = p[3*i+2];
    }
    if (t == 0) whist[0] = 0;     // sample 0 is index 0
    __syncthreads();
    float qx[16], qy[16], qz[16], d[16];
#pragma unroll
    for (int r = 0; r < 16; ++r) {
      int i = t * 16 + r;
      qx[r] = px[i]; qy[r] = py[i]; qz[r] = pz[i];
      d[r] = F32_INF;             // min(inf, d0) == d0 exactly
    }
    int w = 0;
    const size_t cb = (size_t)b * MC * 3;
    for (int it = 1; it < MC; ++it) {
      float wx = px[w], wy = py[w], wz = pz[w];
      float bd = -1.0f; int br = 0;
#pragma unroll
      for (int r = 0; r < 16; ++r) {   // fused min-update + first-max argmax
        float nd = dist2e(qx[r], qy[r], qz[r], wx, wy, wz);
        float dv = fminf(d[r], nd);
        d[r] = dv;
        if (dv > bd) { bd = dv; br = r; }
      }
      unsigned gi = (unsigned)(t * 16 + br);
      ull key = ((ull)__float_as_uint(bd) << 32) | (ull)(unsigned)~gi;
      key = kred<0x111>(key);  // row_shr:1
      key = kred<0x112>(key);  // row_shr:2
      key = kred<0x114>(key);  // row_shr:4
      key = kred<0x118>(key);  // row_shr:8
      key = kred<0x142>(key);  // row_bcast:15
      key = kred<0x143>(key);  // row_bcast:31 -> lane 63 = wave max
      const int par = it & 1;
      if (lane == 63) kbuf[par][wv] = key;
      __syncthreads();
      ull k0 = kbuf[par][0], k1 = kbuf[par][1], k2 = kbuf[par][2], k3 = kbuf[par][3];
      ull ka = (k0 > k1) ? k0 : k1;
      ull kb2 = (k2 > k3) ? k2 : k3;
      ull km = (ka > kb2) ? ka : kb2;
      w = (int)~(unsigned)(km & 0xffffffffULL);
      if (t == 0) whist[it] = w;
      if ((it & 31) == 0) {            // progressive publish, every 32 iters
        if (t < 96) {                  // rows [it-32, it)
          int rq = t / 3, comp = t - rq * 3;
          int row = (it - 32) + rq;
          int wi = whist[row];
          float val = (comp == 0) ? px[wi] : ((comp == 1) ? py[wi] : pz[wi]);
          __hip_atomic_store(ctru + cb + (size_t)row * 3 + comp,
                             __float_as_uint(val), __ATOMIC_RELAXED, SCOPE_AGENT);
        }
        // flag covers rows < it-32: their stores retired at a prior barrier's vmcnt(0)
        if (t == 0)
          __hip_atomic_store(flags + b * 32, (unsigned)(it - 32),
                             __ATOMIC_RELEASE, SCOPE_AGENT);
      }
    }
    __syncthreads();
    if (t < 96) {                      // final rows [992, 1024)
      int rq = t / 3, comp = t - rq * 3;
      int row = 992 + rq;
      int wi = whist[row];
      float val = (comp == 0) ? px[wi] : ((comp == 1) ? py[wi] : pz[wi]);
      __hip_atomic_store(ctru + cb + (size_t)row * 3 + comp,
                         __float_as_uint(val), __ATOMIC_RELAXED, SCOPE_AGENT);
    }
    for (int s = t; s < MC; s += 256) {   // outputs 1 & 2 (normal stores)
      int wi = whist[s];
      size_t o = (size_t)b * MC + s;
      cent_out[3*o] = px[wi]; cent_out[3*o+1] = py[wi]; cent_out[3*o+2] = pz[wi];
      batch_out[o] = (float)b;           // batch = arange // NP == cloud index
    }
    __syncthreads();                     // vmcnt(0): all atomic stores retired
    if (t == 0)
      __hip_atomic_store(flags + b * 32, 1024u, __ATOMIC_RELEASE, SCOPE_AGENT);
    return;
  }

  // ================= CONSUMER: 32 centers of cloud b =================
  const int ck = blk - NB;               // 0..511
  const int b = ck >> 5;                 // cloud
  const int jb = ck & 31;                // within-cloud block
  char* wreg = smem + wv * 9216;         // per-wave region
  float* ld = (float*)wreg;              // scan scratch (dead before hbuf use)
  int*   li = (int*)(wreg + 2048);
  int*   nsel = (int*)(wreg + 4096);
  ushort_t* hb = (ushort_t*)wreg;        // 64 x HSTRIDE hbuf overlays scratch
  const int quad = lane >> 4, col16 = lane & 15;
  const size_t bbase = (size_t)b * NP;
  const float* p = point + bbase * 3;
  const float R2 = (float)(0.2 * 0.2);

  for (int u = 0; u < 8; ++u) {
    const int lc = jb * 32 + u * 4 + wv;
    const int c = b * MC + lc;
    // RELAXED poll (no cache-invalidate side effects); s_sleep waves don't issue
    while (__hip_atomic_load(flags + b * 32, __ATOMIC_RELAXED, SCOPE_AGENT)
           < (unsigned)(lc + 1))
      __builtin_amdgcn_s_sleep(16);
    const float cx = __uint_as_float(
        __hip_atomic_load(ctru + (size_t)c * 3 + 0, __ATOMIC_RELAXED, SCOPE_AGENT));
    const float cy = __uint_as_float(
        __hip_atomic_load(ctru + (size_t)c * 3 + 1, __ATOMIC_RELAXED, SCOPE_AGENT));
    const float cz = __uint_as_float(
        __hip_atomic_load(ctru + (size_t)c * 3 + 2, __ATOMIC_RELAXED, SCOPE_AGENT));

    // ---- neigh: compact in-ball candidates, tau set-selection (r8 proven) ----
    int cnt = 0;
    for (int s = 0; s < NP / 64; ++s) {
      int jj = s * 64 + lane;
      float d2 = dist2e(cx, cy, cz, p[3*jj], p[3*jj+1], p[3*jj+2]);
      bool v = d2 < R2;
      ull m = __ballot(v);
      if (v) {
        int pos = cnt + __popcll(m & ((1ull << lane) - 1ull));
        if (pos < 512) { ld[pos] = d2; li[pos] = jj; }
      }
      cnt += __popcll(m);
    }
    if (cnt > 512) cnt = 512;
    const int nv = (cnt < KNN) ? cnt : KNN;
    int jg;
    if (cnt <= KNN) {
      jg = (lane < cnt) ? li[lane] : 0;  // set-equivalent under masked max-agg
    } else {
      unsigned ob[8]; int oi[8];
#pragma unroll
      for (int r = 0; r < 8; ++r) {
        int s2 = lane + r * 64;
        if (s2 < cnt) { ob[r] = __float_as_uint(ld[s2]); oi[r] = li[s2]; }
        else { ob[r] = 0xFFFFFFFFu; oi[r] = 0; }
      }
      unsigned L = 0u, H = 0x3D23D70Au;  // all candidate bits < bits(0.04f)
      while (L < H) {                    // tau = KNN-th smallest d2 bit pattern
        unsigned mid = (L + H) >> 1;
        int cle = 0;
#pragma unroll
        for (int r = 0; r < 8; ++r) cle += (int)__popcll(__ballot(ob[r] <= mid));
        if (cle >= KNN) H = mid; else L = mid + 1;
      }
      const unsigned tau = H;
      int c_lt = 0;
#pragma unroll
      for (int r = 0; r < 8; ++r) c_lt += (int)__popcll(__ballot(ob[r] < tau));
      const int need = KNN - c_lt;
      const ull below = (1ull << lane) - 1ull;
      int outpos = 0, eqc = 0;
#pragma unroll
      for (int r = 0; r < 8; ++r) {      // slot order == index order (stable ties)
        ull meq = __ballot(ob[r] == tau);
        int eqrank = eqc + (int)__popcll(meq & below);
        bool sel = (ob[r] < tau) || ((ob[r] == tau) && (eqrank < need));
        ull msel = __ballot(sel);
        if (sel) nsel[outpos + (int)__popcll(msel & below)] = oi[r];
        outpos += (int)__popcll(msel);
        eqc += (int)__popcll(meq);
      }
      jg = nsel[lane];
    }

    // ---- MFMA bf16 MLP for center c (r8 body) ----
    const float* pp = point + (bbase + jg) * 3;
    const float dx = pp[0] - cx, dy = pp[1] - cy, dz = pp[2] - cz;
    bf16x8 a1[4][2];
    bf16x8 a2[4];
#pragma unroll
    for (int mt = 0; mt < 4; ++mt) {
      int srcl = mt * 16 + col16;
      int jmt = __shfl(jg, srcl);
      const ushort_t* rp = xyzbf + (bbase + (size_t)jmt) * CIN + quad * 8;
      a1[mt][0] = *(const bf16x8*)(rp);
      a1[mt][1] = *(const bf16x8*)(rp + 32);
      float ddx = __shfl(dx, srcl), ddy = __shfl(dy, srcl), ddz = __shfl(dz, srcl);
      bf16x8 t2 = {0, 0, 0, 0, 0, 0, 0, 0};
      if (quad == 0) {
        t2[0] = (short)f2bf(ddx); t2[1] = (short)f2bf(ddy); t2[2] = (short)f2bf(ddz);
      }
      a2[mt] = t2;
    }
    bf16x8 bw1[4][3];
#pragma unroll
    for (int nt = 0; nt < 4; ++nt)
#pragma unroll
      for (int ks = 0; ks < 3; ++ks)
        bw1[nt][ks] = *(const bf16x8*)(w1f + ((size_t)(nt * 3 + ks) * 64 + lane) * 8);
    f32x4 acc1[4][4];
#pragma unroll
    for (int nt = 0; nt < 4; ++nt) {
      float bv = b1[nt * 16 + col16];
#pragma unroll
      for (int mt = 0; mt < 4; ++mt) { f32x4 v = {bv, bv, bv, bv}; acc1[mt][nt] = v; }
    }
#pragma unroll
    for (int mt = 0; mt < 4; ++mt)
#pragma unroll
      for (int nt = 0; nt < 4; ++nt) {
        acc1[mt][nt] = __builtin_amdgcn_mfma_f32_16x16x32_bf16(a1[mt][0], bw1[nt][0], acc1[mt][nt], 0, 0, 0);
        acc1[mt][nt] = __builtin_amdgcn_mfma_f32_16x16x32_bf16(a1[mt][1], bw1[nt][1], acc1[mt][nt], 0, 0, 0);
        acc1[mt][nt] = __builtin_amdgcn_mfma_f32_16x16x32_bf16(a2[mt],    bw1[nt][2], acc1[mt][nt], 0, 0, 0);
      }
#pragma unroll
    for (int mt = 0; mt < 4; ++mt)
#pragma unroll
      for (int nt = 0; nt < 4; ++nt)
#pragma unroll
        for (int reg = 0; reg < 4; ++reg) {
          int row = quad * 4 + reg + mt * 16;
          hb[row * HSTRIDE + col16 + nt * 16] = f2bf(fmaxf(acc1[mt][nt][reg], 0.f));
        }
    bf16x8 a21[4][2];
#pragma unroll
    for (int mt = 0; mt < 4; ++mt)
#pragma unroll
      for (int ks = 0; ks < 2; ++ks)
        a21[mt][ks] = *(const bf16x8*)(hb + (col16 + mt * 16) * HSTRIDE + ks * 32 + quad * 8);
    bf16x8 bw2[4][2];
#pragma unroll
    for (int nt = 0; nt < 4; ++nt)
#pragma unroll
      for (int ks = 0; ks < 2; ++ks)
        bw2[nt][ks] = *(const bf16x8*)(w2f + ((size_t)(nt * 2 + ks) * 64 + lane) * 8);
    f32x4 acc2[4][4];
#pragma unroll
    for (int nt = 0; nt < 4; ++nt) {
      float bv = b2[nt * 16 + col16];
#pragma unroll
      for (int mt = 0; mt < 4; ++mt) { f32x4 v = {bv, bv, bv, bv}; acc2[mt][nt] = v; }
    }
#pragma unroll
    for (int mt = 0; mt < 4; ++mt)
#pragma unroll
      for (int nt = 0; nt < 4; ++nt) {
        acc2[mt][nt] = __builtin_amdgcn_mfma_f32_16x16x32_bf16(a21[mt][0], bw2[nt][0], acc2[mt][nt], 0, 0, 0);
        acc2[mt][nt] = __builtin_amdgcn_mfma_f32_16x16x32_bf16(a21[mt][1], bw2[nt][1], acc2[mt][nt], 0, 0, 0);
      }
#pragma unroll
    for (int mt = 0; mt < 4; ++mt)
#pragma unroll
      for (int nt = 0; nt < 4; ++nt)
#pragma unroll
        for (int reg = 0; reg < 4; ++reg) {
          int row = quad * 4 + reg + mt * 16;
          hb[row * HSTRIDE + col16 + nt * 16] = f2bf(fmaxf(acc2[mt][nt][reg], 0.f));
        }
    bf16x8 a3[4][2];
#pragma unroll
    for (int mt = 0; mt < 4; ++mt)
#pragma unroll
      for (int ks = 0; ks < 2; ++ks)
        a3[mt][ks] = *(const bf16x8*)(hb + (col16 + mt * 16) * HSTRIDE + ks * 32 + quad * 8);
#pragma unroll
    for (int pass = 0; pass < 2; ++pass) {
      bf16x8 bw3[4][2];
#pragma unroll
      for (int nt = 0; nt < 4; ++nt)
#pragma unroll
        for (int ks = 0; ks < 2; ++ks)
          bw3[nt][ks] = *(const bf16x8*)(w3f + ((size_t)((pass * 4 + nt) * 2 + ks) * 64 + lane) * 8);
      f32x4 acc3[4][4];
#pragma unroll
      for (int nt = 0; nt < 4; ++nt) {
        float bv = b3[pass * 64 + nt * 16 + col16];
#pragma unroll
        for (int mt = 0; mt < 4; ++mt) { f32x4 v = {bv, bv, bv, bv}; acc3[mt][nt] = v; }
      }
#pragma unroll
      for (int mt = 0; mt < 4; ++mt)
#pragma unroll
        for (int nt = 0; nt < 4; ++nt) {
          acc3[mt][nt] = __builtin_amdgcn_mfma_f32_16x16x32_bf16(a3[mt][0], bw3[nt][0], acc3[mt][nt], 0, 0, 0);
          acc3[mt][nt] = __builtin_amdgcn_mfma_f32_16x16x32_bf16(a3[mt][1], bw3[nt][1], acc3[mt][nt], 0, 0, 0);
        }
#pragma unroll
      for (int nt = 0; nt < 4; ++nt) {
        float m = -1.0e30f;
#pragma unroll
        for (int mt = 0; mt < 4; ++mt)
#pragma unroll
          for (int reg = 0; reg < 4; ++reg) {
            int row = quad * 4 + reg + mt * 16;
            float v = fmaxf(acc3[mt][nt][reg], 0.f);
            m = fmaxf(m, (row < nv) ? v : -1.0e30f);
          }
        m = fmaxf(m, __shfl_xor(m, 16));
        m = fmaxf(m, __shfl_xor(m, 32));
        if (quad == 0)
          out[(size_t)c * OUTD + pass * 64 + nt * 16 + col16] = m;
      }
    }
  }
}

extern "C" void kernel_launch(void* const* d_in, const int* in_sizes, int n_in,
                              void* d_out, int out_size, void* d_ws, size_t ws_size,
                              hipStream_t stream) {
  const float* xyz   = (const float*)d_in[0];
  const float* point = (const float*)d_in[1];
  // d_in[2] = batch (values == cloud index by construction), d_in[3] = num_samples (64)
  const float* W1 = (const float*)d_in[4];
  const float* b1 = (const float*)d_in[5];
  const float* W2 = (const float*)d_in[6];
  const float* b2 = (const float*)d_in[7];
  const float* W3 = (const float*)d_in[8];
  const float* b3 = (const float*)d_in[9];

  float* out       = (float*)d_out;                     // [16384,128]
  float* cent_out  = out + (size_t)NB * MC * OUTD;      // [16384,3]
  float* batch_out = cent_out + (size_t)NB * MC * 3;    // [16384] (f32 values)

  char* ws = (char*)d_ws;
  unsigned* flags  = (unsigned*)ws;                         // 4096 B (progress flags)
  float* ctr       = (float*)(ws + 4096);                   // 196608 B
  ushort_t* xyzbf  = (ushort_t*)(ws + 4456448);             // 8 MB
  ushort_t* w1f    = (ushort_t*)(ws + 4456448 + 8388608);   // 12288 B
  ushort_t* w2f    = (ushort_t*)(ws + 12845056 + 12288);    // 8192 B
  ushort_t* w3f    = (ushort_t*)(ws + 12857344 + 8192);     // 16384 B

  // Flags MUST be zeroed (harness poisons ws with 0xAA, which would read as "ready").
  hipMemsetAsync(ws, 0, 4096, stream);
  prep_kernel<<<4097, 256, 0, stream>>>(xyz, W1, W2, W3, xyzbf, w1f, w2f, w3f);
  fps_cons_kernel<<<NB + 512, 256, 0, stream>>>(
      point, b1, b2, b3, flags, ctr, xyzbf, w1f, w2f, w3f, out, cent_out, batch_out);
}